// Round 4
// baseline (348.931 us; speedup 1.0000x reference)
//
#include <hip/hip_runtime.h>
#include <stdint.h>

typedef unsigned short u16;
typedef __bf16 bf16x8 __attribute__((ext_vector_type(8)));
typedef float f32x4 __attribute__((ext_vector_type(4)));
typedef unsigned short u16x8 __attribute__((ext_vector_type(8)));

__device__ __forceinline__ u16 f2bf(float f) {
  union { float f; uint32_t u; } x; x.f = f;
  uint32_t r = x.u + 0x7fffu + ((x.u >> 16) & 1u);   // RNE
  return (u16)(r >> 16);
}

// ---------- fused prologue: A fp32->bf16 and W q8_0->bf16 in one dispatch ----------
__global__ __launch_bounds__(256) void cvt_all(
    const float* __restrict__ A, u16* __restrict__ Ab, size_t n8a,
    const int* __restrict__ Wq, const float* __restrict__ S,
    u16* __restrict__ Wb, size_t n8w) {
  size_t i = (size_t)blockIdx.x * 256 + threadIdx.x;
  if (i < n8a) {
    const float4* p = (const float4*)(A + i * 8);
    float4 v0 = p[0], v1 = p[1];
    u16x8 r = { f2bf(v0.x), f2bf(v0.y), f2bf(v0.z), f2bf(v0.w),
                f2bf(v1.x), f2bf(v1.y), f2bf(v1.z), f2bf(v1.w) };
    *(u16x8*)(Ab + i * 8) = r;
  } else {
    size_t j = i - n8a;
    if (j >= n8w) return;
    const int4* p = (const int4*)(Wq + j * 8);
    int4 v0 = p[0], v1 = p[1];
    float s = S[j >> 2];
    u16x8 r = { f2bf((float)(v0.x - 128) * s), f2bf((float)(v0.y - 128) * s),
                f2bf((float)(v0.z - 128) * s), f2bf((float)(v0.w - 128) * s),
                f2bf((float)(v1.x - 128) * s), f2bf((float)(v1.y - 128) * s),
                f2bf((float)(v1.z - 128) * s), f2bf((float)(v1.w - 128) * s) };
    *(u16x8*)(Wb + j * 8) = r;
  }
}

#define BM 256
#define BN 128
#define BK 32

__device__ __forceinline__ void load_lds_16B(const void* g, void* l) {
  __builtin_amdgcn_global_load_lds(
      (const __attribute__((address_space(1))) unsigned int*)g,
      (__attribute__((address_space(3))) unsigned int*)l, 16, 0, 0);
}

// ---------- MODE 0: A-frags direct from global, B via double-buffered LDS ----------
// Block 256x128, 4 waves, wave tile 64x128 (disjoint A rows per wave; B shared).
// One barrier per K-iter; B staging + next A-frag loads issued a full MFMA
// block before the barrier's vmcnt drain.
__global__ __launch_bounds__(256, 2) void gemm_dbuf(
    const u16* __restrict__ Ab, const u16* __restrict__ Wb,
    float* __restrict__ C, int M, int N, int K) {
  __shared__ u16 Bs[2 * BN * BK];   // 2 x 8 KB

  const int tid = threadIdx.x;
  const int wave = tid >> 6, lane = tid & 63;
  const int m0 = blockIdx.y * BM, n0 = blockIdx.x * BN;
  const int wm = wave * 64;
  const int lrow = lane & 15, lq = lane >> 4;

  // A-frag global pointers (k0-invariant): 16 contiguous B per frag
  const u16* pA[4];
  #pragma unroll
  for (int i = 0; i < 4; ++i)
    pA[i] = Ab + (size_t)(m0 + wm + i * 16 + lrow) * K + lq * 8;

  // B staging (swizzled source: slot s of row r holds chunk (s-(r>>1))&3)
  const u16* gB[2]; u16* dB[2];
  #pragma unroll
  for (int it = 0; it < 2; ++it) {
    int q = wave * 128 + it * 64 + lane;   // 512 16B-chunks
    int row = q >> 2, s = q & 3;
    int c = (s - (row >> 1)) & 3;
    gB[it] = Wb + (size_t)(n0 + row) * K + c * 8;
    dB[it] = Bs + (size_t)(wave * 128 + it * 64) * 8;
  }

  // B fragment LDS addresses (swizzle lookup), buffer 0
  const u16* fB[8];
  #pragma unroll
  for (int j = 0; j < 8; ++j) {
    int row = j * 16 + lrow;
    int s = (lq + (row >> 1)) & 3;
    fB[j] = Bs + row * BK + s * 8;
  }

  f32x4 acc[4][8] = {};
  bf16x8 a0[4], a1[4];

  // prologue: stage B(k=0) into buf0, load A-frags(k=0)
  #pragma unroll
  for (int it = 0; it < 2; ++it) load_lds_16B(gB[it], dB[it]);
  #pragma unroll
  for (int i = 0; i < 4; ++i) a0[i] = *(const bf16x8*)(pA[i]);
  __syncthreads();

  const int NT = K / BK;   // 128, even
  for (int t = 0; t < NT; t += 2) {
    // ---- even iter: read buf0 + a0, prefetch buf1 + a1 ----
    {
      const int kn = (t + 1) * BK;
      #pragma unroll
      for (int it = 0; it < 2; ++it) load_lds_16B(gB[it] + kn, dB[it] + BN * BK);
      #pragma unroll
      for (int i = 0; i < 4; ++i) a1[i] = *(const bf16x8*)(pA[i] + kn);
      bf16x8 b[8];
      #pragma unroll
      for (int j = 0; j < 8; ++j) b[j] = *(const bf16x8*)fB[j];
      #pragma unroll
      for (int i = 0; i < 4; ++i)
        #pragma unroll
        for (int j = 0; j < 8; ++j)
          acc[i][j] = __builtin_amdgcn_mfma_f32_16x16x32_bf16(a0[i], b[j], acc[i][j], 0, 0, 0);
      __syncthreads();
    }
    // ---- odd iter: read buf1 + a1, prefetch buf0 + a0 ----
    {
      const int kn = (t + 2) * BK;
      if (t + 2 < NT) {
        #pragma unroll
        for (int it = 0; it < 2; ++it) load_lds_16B(gB[it] + kn, dB[it]);
        #pragma unroll
        for (int i = 0; i < 4; ++i) a0[i] = *(const bf16x8*)(pA[i] + kn);
      }
      bf16x8 b[8];
      #pragma unroll
      for (int j = 0; j < 8; ++j) b[j] = *(const bf16x8*)(fB[j] + BN * BK);
      #pragma unroll
      for (int i = 0; i < 4; ++i)
        #pragma unroll
        for (int j = 0; j < 8; ++j)
          acc[i][j] = __builtin_amdgcn_mfma_f32_16x16x32_bf16(a1[i], b[j], acc[i][j], 0, 0, 0);
      __syncthreads();
    }
  }

  // epilogue: C/D layout col=lane&15 (n), row=(lane>>4)*4+reg (m)
  #pragma unroll
  for (int i = 0; i < 4; ++i) {
    #pragma unroll
    for (int r = 0; r < 4; ++r) {
      int gm = m0 + wm + i * 16 + lq * 4 + r;
      float* crow = C + (size_t)gm * N + n0 + lrow;
      #pragma unroll
      for (int j = 0; j < 8; ++j) crow[j * 16] = acc[i][j][r];
    }
  }
}

// ---------- fallback (MODE 1: A fused, B ws; MODE 2: both fused) ----------
template <int MODE>
__global__ __launch_bounds__(256, 2) void gemm_fb(
    const u16* __restrict__ Wb,
    const float* __restrict__ Af, const int* __restrict__ Wq,
    const float* __restrict__ Sc, float* __restrict__ C,
    int M, int N, int K) {
  __shared__ u16 As[BM * BK];
  __shared__ u16 Bs[BN * BK];

  const int tid = threadIdx.x;
  const int wave = tid >> 6, lane = tid & 63;
  const int m0 = blockIdx.y * BM, n0 = blockIdx.x * BN;
  const int wm = (wave & 1) * 128, wn = (wave >> 1) * 64;
  const int lrow = lane & 15, lq = lane >> 4;

  const u16* gB[2]; u16* dB[2];
  if constexpr (MODE == 1) {
    #pragma unroll
    for (int it = 0; it < 2; ++it) {
      int q = wave * 128 + it * 64 + lane;
      int row = q >> 2, s = q & 3;
      int c = (s - (row >> 1)) & 3;
      gB[it] = Wb + (size_t)(n0 + row) * K + c * 8;
      dB[it] = Bs + (size_t)(wave * 128 + it * 64) * 8;
    }
  }

  const u16* fA[8]; const u16* fB[4];
  #pragma unroll
  for (int i = 0; i < 8; ++i) {
    int row = wm + i * 16 + lrow;
    int s = (lq + (row >> 1)) & 3;
    fA[i] = As + row * BK + s * 8;
  }
  #pragma unroll
  for (int j = 0; j < 4; ++j) {
    int row = wn + j * 16 + lrow;
    int s = (lq + (row >> 1)) & 3;
    fB[j] = Bs + row * BK + s * 8;
  }

  f32x4 acc[8][4] = {};

  for (int k0 = 0; k0 < K; k0 += BK) {
    #pragma unroll
    for (int it = 0; it < 4; ++it) {
      int g = it * 256 + tid;
      int row = g >> 2, c8 = g & 3;
      int s = (c8 + (row >> 1)) & 3;
      const float4* p = (const float4*)(Af + (size_t)(m0 + row) * K + k0 + c8 * 8);
      float4 v0 = p[0], v1 = p[1];
      u16x8 r = { f2bf(v0.x), f2bf(v0.y), f2bf(v0.z), f2bf(v0.w),
                  f2bf(v1.x), f2bf(v1.y), f2bf(v1.z), f2bf(v1.w) };
      *(u16x8*)(As + row * BK + s * 8) = r;
    }
    if constexpr (MODE == 1) {
      #pragma unroll
      for (int it = 0; it < 2; ++it) load_lds_16B(gB[it] + k0, dB[it]);
    } else {
      #pragma unroll
      for (int it = 0; it < 2; ++it) {
        int g = it * 256 + tid;
        int row = g >> 2, c8 = g & 3;
        int s = (c8 + (row >> 1)) & 3;
        const int4* p = (const int4*)(Wq + (size_t)(n0 + row) * K + k0 + c8 * 8);
        int4 v0 = p[0], v1 = p[1];
        float sc = Sc[(size_t)(n0 + row) * (K >> 5) + (k0 >> 5)];
        u16x8 r = { f2bf((float)(v0.x - 128) * sc), f2bf((float)(v0.y - 128) * sc),
                    f2bf((float)(v0.z - 128) * sc), f2bf((float)(v0.w - 128) * sc),
                    f2bf((float)(v1.x - 128) * sc), f2bf((float)(v1.y - 128) * sc),
                    f2bf((float)(v1.z - 128) * sc), f2bf((float)(v1.w - 128) * sc) };
        *(u16x8*)(Bs + row * BK + s * 8) = r;
      }
    }
    __syncthreads();

    bf16x8 a[8], b[4];
    #pragma unroll
    for (int i = 0; i < 8; ++i) a[i] = *(const bf16x8*)fA[i];
    #pragma unroll
    for (int j = 0; j < 4; ++j) b[j] = *(const bf16x8*)fB[j];
    #pragma unroll
    for (int i = 0; i < 8; ++i)
      #pragma unroll
      for (int j = 0; j < 4; ++j)
        acc[i][j] = __builtin_amdgcn_mfma_f32_16x16x32_bf16(a[i], b[j], acc[i][j], 0, 0, 0);
    __syncthreads();
  }

  #pragma unroll
  for (int i = 0; i < 8; ++i) {
    #pragma unroll
    for (int r = 0; r < 4; ++r) {
      int gm = m0 + wm + i * 16 + lq * 4 + r;
      float* crow = C + (size_t)gm * N + n0 + wn + lrow;
      #pragma unroll
      for (int j = 0; j < 4; ++j) crow[j * 16] = acc[i][j][r];
    }
  }
}

extern "C" void kernel_launch(void* const* d_in, const int* in_sizes, int n_in,
                              void* d_out, int out_size, void* d_ws, size_t ws_size,
                              hipStream_t stream) {
  const float* A  = (const float*)d_in[0];
  const int*   Wq = (const int*)d_in[1];
  const float* S  = (const float*)d_in[2];
  float* C = (float*)d_out;

  const int K = 4096;                 // I (infeatures)
  const int N = in_sizes[1] / K;      // O = 4096
  const int M = in_sizes[0] / K;      // B*S = 4096

  const size_t needA = (size_t)M * K * sizeof(u16);   // 32 MB
  const size_t needW = (size_t)N * K * sizeof(u16);   // 32 MB
  dim3 grid(N / BN, M / BM), blk(256);

  if (ws_size >= needA + needW) {
    u16* Ab = (u16*)d_ws;
    u16* Wb = (u16*)((char*)d_ws + needA);
    size_t nA8 = (size_t)M * K / 8, nW8 = (size_t)N * K / 8;
    cvt_all<<<(int)((nA8 + nW8 + 255) / 256), 256, 0, stream>>>(A, Ab, nA8, Wq, S, Wb, nW8);
    gemm_dbuf<<<grid, blk, 0, stream>>>(Ab, Wb, C, M, N, K);
  } else if (ws_size >= needW) {
    u16* Wb = (u16*)d_ws;
    size_t nW8 = (size_t)N * K / 8;
    cvt_all<<<(int)((nW8 + 255) / 256), 256, 0, stream>>>(nullptr, nullptr, 0, Wq, S, Wb, nW8);
    gemm_fb<1><<<grid, blk, 0, stream>>>(Wb, A, nullptr, nullptr, C, M, N, K);
  } else {
    gemm_fb<2><<<grid, blk, 0, stream>>>(nullptr, A, Wq, S, C, M, N, K);
  }
}

// Round 5
// 313.322 us; speedup vs baseline: 1.1136x; 1.1136x over previous
//
#include <hip/hip_runtime.h>
#include <stdint.h>

typedef unsigned short u16;
typedef __bf16 bf16x8 __attribute__((ext_vector_type(8)));
typedef float f32x4 __attribute__((ext_vector_type(4)));
typedef unsigned short u16x8 __attribute__((ext_vector_type(8)));

__device__ __forceinline__ u16 f2bf(float f) {
  union { float f; uint32_t u; } x; x.f = f;
  uint32_t r = x.u + 0x7fffu + ((x.u >> 16) & 1u);   // RNE
  return (u16)(r >> 16);
}

// ---------- fused prologue: A fp32->bf16 and W q8_0->bf16 in one dispatch ----------
__global__ __launch_bounds__(256) void cvt_all(
    const float* __restrict__ A, u16* __restrict__ Ab, size_t n8a,
    const int* __restrict__ Wq, const float* __restrict__ S,
    u16* __restrict__ Wb, size_t n8w) {
  size_t i = (size_t)blockIdx.x * 256 + threadIdx.x;
  if (i < n8a) {
    const float4* p = (const float4*)(A + i * 8);
    float4 v0 = p[0], v1 = p[1];
    u16x8 r = { f2bf(v0.x), f2bf(v0.y), f2bf(v0.z), f2bf(v0.w),
                f2bf(v1.x), f2bf(v1.y), f2bf(v1.z), f2bf(v1.w) };
    *(u16x8*)(Ab + i * 8) = r;
  } else {
    size_t j = i - n8a;
    if (j >= n8w) return;
    const int4* p = (const int4*)(Wq + j * 8);
    int4 v0 = p[0], v1 = p[1];
    float s = S[j >> 2];
    u16x8 r = { f2bf((float)(v0.x - 128) * s), f2bf((float)(v0.y - 128) * s),
                f2bf((float)(v0.z - 128) * s), f2bf((float)(v0.w - 128) * s),
                f2bf((float)(v1.x - 128) * s), f2bf((float)(v1.y - 128) * s),
                f2bf((float)(v1.z - 128) * s), f2bf((float)(v1.w - 128) * s) };
    *(u16x8*)(Wb + j * 8) = r;
  }
}

#define BM 256
#define BN 128
#define BK 32

__device__ __forceinline__ void load_lds_16B(const void* g, void* l) {
  __builtin_amdgcn_global_load_lds(
      (const __attribute__((address_space(1))) unsigned int*)g,
      (__attribute__((address_space(3))) unsigned int*)l, 16, 0, 0);
}

// ---------- main GEMM: double-buffered LDS, staging for t+1 issued at top of t,
// ONE __syncthreads per K-iter at the end. The vmcnt(0) drain at the barrier
// hits loads that aged through the full ds_read+MFMA body (vs R3's zero-aging
// drain right after issue). All staging via global_load_lds (placement holds;
// R4 showed VGPR-prefetch gets sunk to the barrier by the scheduler).
__global__ __launch_bounds__(256, 2) void gemm_db2(
    const u16* __restrict__ Ab, const u16* __restrict__ Wb,
    float* __restrict__ C, int M, int N, int K) {
  __shared__ u16 As[2 * BM * BK];   // 2 x 16 KB
  __shared__ u16 Bs[2 * BN * BK];   // 2 x  8 KB

  const int tid = threadIdx.x;
  const int wave = tid >> 6, lane = tid & 63;
  const int m0 = blockIdx.y * BM, n0 = blockIdx.x * BN;
  const int wm = (wave & 1) * 128, wn = (wave >> 1) * 64;
  const int lrow = lane & 15, lq = lane >> 4;

  // staging addresses (k0-invariant), swizzled source:
  // slot s of row r holds global 16B-chunk (s - (r>>1)) & 3
  const u16* gA[4]; u16* dA[4];
  const u16* gB[2]; u16* dB[2];
  #pragma unroll
  for (int it = 0; it < 4; ++it) {            // A: 1024 chunks
    int q = wave * 256 + it * 64 + lane;
    int row = q >> 2, s = q & 3;
    int c = (s - (row >> 1)) & 3;
    gA[it] = Ab + (size_t)(m0 + row) * K + c * 8;
    dA[it] = As + (size_t)(wave * 256 + it * 64) * 8;
  }
  #pragma unroll
  for (int it = 0; it < 2; ++it) {            // B: 512 chunks
    int q = wave * 128 + it * 64 + lane;
    int row = q >> 2, s = q & 3;
    int c = (s - (row >> 1)) & 3;
    gB[it] = Wb + (size_t)(n0 + row) * K + c * 8;
    dB[it] = Bs + (size_t)(wave * 128 + it * 64) * 8;
  }

  // fragment LDS addresses (swizzle lookup), buffer 0
  const u16* fA[8]; const u16* fB[4];
  #pragma unroll
  for (int i = 0; i < 8; ++i) {
    int row = wm + i * 16 + lrow;
    int s = (lq + (row >> 1)) & 3;
    fA[i] = As + row * BK + s * 8;
  }
  #pragma unroll
  for (int j = 0; j < 4; ++j) {
    int row = wn + j * 16 + lrow;
    int s = (lq + (row >> 1)) & 3;
    fB[j] = Bs + row * BK + s * 8;
  }

  f32x4 acc[8][4] = {};

  // prologue: stage k=0 into buf0
  #pragma unroll
  for (int it = 0; it < 4; ++it) load_lds_16B(gA[it], dA[it]);
  #pragma unroll
  for (int it = 0; it < 2; ++it) load_lds_16B(gB[it], dB[it]);
  __syncthreads();

  const int NT = K / BK;   // 128, even
  for (int t = 0; t < NT; t += 2) {
    // ---- even: stage k(t+1) -> buf1, compute from buf0 ----
    {
      const int kn = (t + 1) * BK;   // t+1 <= NT-1, always valid
      #pragma unroll
      for (int it = 0; it < 4; ++it) load_lds_16B(gA[it] + kn, dA[it] + BM * BK);
      #pragma unroll
      for (int it = 0; it < 2; ++it) load_lds_16B(gB[it] + kn, dB[it] + BN * BK);
      bf16x8 a[8], b[4];
      #pragma unroll
      for (int i = 0; i < 8; ++i) a[i] = *(const bf16x8*)fA[i];
      #pragma unroll
      for (int j = 0; j < 4; ++j) b[j] = *(const bf16x8*)fB[j];
      #pragma unroll
      for (int i = 0; i < 8; ++i)
        #pragma unroll
        for (int j = 0; j < 4; ++j)
          acc[i][j] = __builtin_amdgcn_mfma_f32_16x16x32_bf16(a[i], b[j], acc[i][j], 0, 0, 0);
      __syncthreads();
    }
    // ---- odd: stage k(t+2) -> buf0 (wrap to 0 on last), compute from buf1 ----
    {
      const int kn = (t + 2 < NT) ? (t + 2) * BK : 0;  // redundant stage on last iter
      #pragma unroll
      for (int it = 0; it < 4; ++it) load_lds_16B(gA[it] + kn, dA[it]);
      #pragma unroll
      for (int it = 0; it < 2; ++it) load_lds_16B(gB[it] + kn, dB[it]);
      bf16x8 a[8], b[4];
      #pragma unroll
      for (int i = 0; i < 8; ++i) a[i] = *(const bf16x8*)(fA[i] + BM * BK);
      #pragma unroll
      for (int j = 0; j < 4; ++j) b[j] = *(const bf16x8*)(fB[j] + BN * BK);
      #pragma unroll
      for (int i = 0; i < 8; ++i)
        #pragma unroll
        for (int j = 0; j < 4; ++j)
          acc[i][j] = __builtin_amdgcn_mfma_f32_16x16x32_bf16(a[i], b[j], acc[i][j], 0, 0, 0);
      __syncthreads();
    }
  }

  // epilogue: C/D layout col=lane&15 (n), row=(lane>>4)*4+reg (m)
  #pragma unroll
  for (int i = 0; i < 8; ++i) {
    #pragma unroll
    for (int r = 0; r < 4; ++r) {
      int gm = m0 + wm + i * 16 + lq * 4 + r;
      float* crow = C + (size_t)gm * N + n0 + wn + lrow;
      #pragma unroll
      for (int j = 0; j < 4; ++j) crow[j * 16] = acc[i][j][r];
    }
  }
}

// ---------- fallback (MODE 1: A fused, B ws; MODE 2: both fused) ----------
template <int MODE>
__global__ __launch_bounds__(256, 2) void gemm_fb(
    const u16* __restrict__ Wb,
    const float* __restrict__ Af, const int* __restrict__ Wq,
    const float* __restrict__ Sc, float* __restrict__ C,
    int M, int N, int K) {
  __shared__ u16 As[BM * BK];
  __shared__ u16 Bs[BN * BK];

  const int tid = threadIdx.x;
  const int wave = tid >> 6, lane = tid & 63;
  const int m0 = blockIdx.y * BM, n0 = blockIdx.x * BN;
  const int wm = (wave & 1) * 128, wn = (wave >> 1) * 64;
  const int lrow = lane & 15, lq = lane >> 4;

  const u16* gB[2]; u16* dB[2];
  if constexpr (MODE == 1) {
    #pragma unroll
    for (int it = 0; it < 2; ++it) {
      int q = wave * 128 + it * 64 + lane;
      int row = q >> 2, s = q & 3;
      int c = (s - (row >> 1)) & 3;
      gB[it] = Wb + (size_t)(n0 + row) * K + c * 8;
      dB[it] = Bs + (size_t)(wave * 128 + it * 64) * 8;
    }
  }

  const u16* fA[8]; const u16* fB[4];
  #pragma unroll
  for (int i = 0; i < 8; ++i) {
    int row = wm + i * 16 + lrow;
    int s = (lq + (row >> 1)) & 3;
    fA[i] = As + row * BK + s * 8;
  }
  #pragma unroll
  for (int j = 0; j < 4; ++j) {
    int row = wn + j * 16 + lrow;
    int s = (lq + (row >> 1)) & 3;
    fB[j] = Bs + row * BK + s * 8;
  }

  f32x4 acc[8][4] = {};

  for (int k0 = 0; k0 < K; k0 += BK) {
    #pragma unroll
    for (int it = 0; it < 4; ++it) {
      int g = it * 256 + tid;
      int row = g >> 2, c8 = g & 3;
      int s = (c8 + (row >> 1)) & 3;
      const float4* p = (const float4*)(Af + (size_t)(m0 + row) * K + k0 + c8 * 8);
      float4 v0 = p[0], v1 = p[1];
      u16x8 r = { f2bf(v0.x), f2bf(v0.y), f2bf(v0.z), f2bf(v0.w),
                  f2bf(v1.x), f2bf(v1.y), f2bf(v1.z), f2bf(v1.w) };
      *(u16x8*)(As + row * BK + s * 8) = r;
    }
    if constexpr (MODE == 1) {
      #pragma unroll
      for (int it = 0; it < 2; ++it) load_lds_16B(gB[it] + k0, dB[it]);
    } else {
      #pragma unroll
      for (int it = 0; it < 2; ++it) {
        int g = it * 256 + tid;
        int row = g >> 2, c8 = g & 3;
        int s = (c8 + (row >> 1)) & 3;
        const int4* p = (const int4*)(Wq + (size_t)(n0 + row) * K + k0 + c8 * 8);
        int4 v0 = p[0], v1 = p[1];
        float sc = Sc[(size_t)(n0 + row) * (K >> 5) + (k0 >> 5)];
        u16x8 r = { f2bf((float)(v0.x - 128) * sc), f2bf((float)(v0.y - 128) * sc),
                    f2bf((float)(v0.z - 128) * sc), f2bf((float)(v0.w - 128) * sc),
                    f2bf((float)(v1.x - 128) * sc), f2bf((float)(v1.y - 128) * sc),
                    f2bf((float)(v1.z - 128) * sc), f2bf((float)(v1.w - 128) * sc) };
        *(u16x8*)(Bs + row * BK + s * 8) = r;
      }
    }
    __syncthreads();

    bf16x8 a[8], b[4];
    #pragma unroll
    for (int i = 0; i < 8; ++i) a[i] = *(const bf16x8*)fA[i];
    #pragma unroll
    for (int j = 0; j < 4; ++j) b[j] = *(const bf16x8*)fB[j];
    #pragma unroll
    for (int i = 0; i < 8; ++i)
      #pragma unroll
      for (int j = 0; j < 4; ++j)
        acc[i][j] = __builtin_amdgcn_mfma_f32_16x16x32_bf16(a[i], b[j], acc[i][j], 0, 0, 0);
    __syncthreads();
  }

  #pragma unroll
  for (int i = 0; i < 8; ++i) {
    #pragma unroll
    for (int r = 0; r < 4; ++r) {
      int gm = m0 + wm + i * 16 + lq * 4 + r;
      float* crow = C + (size_t)gm * N + n0 + wn + lrow;
      #pragma unroll
      for (int j = 0; j < 4; ++j) crow[j * 16] = acc[i][j][r];
    }
  }
}

extern "C" void kernel_launch(void* const* d_in, const int* in_sizes, int n_in,
                              void* d_out, int out_size, void* d_ws, size_t ws_size,
                              hipStream_t stream) {
  const float* A  = (const float*)d_in[0];
  const int*   Wq = (const int*)d_in[1];
  const float* S  = (const float*)d_in[2];
  float* C = (float*)d_out;

  const int K = 4096;                 // I (infeatures)
  const int N = in_sizes[1] / K;      // O = 4096
  const int M = in_sizes[0] / K;      // B*S = 4096

  const size_t needA = (size_t)M * K * sizeof(u16);   // 32 MB
  const size_t needW = (size_t)N * K * sizeof(u16);   // 32 MB
  dim3 grid(N / BN, M / BM), blk(256);

  if (ws_size >= needA + needW) {
    u16* Ab = (u16*)d_ws;
    u16* Wb = (u16*)((char*)d_ws + needA);
    size_t nA8 = (size_t)M * K / 8, nW8 = (size_t)N * K / 8;
    cvt_all<<<(int)((nA8 + nW8 + 255) / 256), 256, 0, stream>>>(A, Ab, nA8, Wq, S, Wb, nW8);
    gemm_db2<<<grid, blk, 0, stream>>>(Ab, Wb, C, M, N, K);
  } else if (ws_size >= needW) {
    u16* Wb = (u16*)d_ws;
    size_t nW8 = (size_t)N * K / 8;
    cvt_all<<<(int)((nW8 + 255) / 256), 256, 0, stream>>>(nullptr, nullptr, 0, Wq, S, Wb, nW8);
    gemm_fb<1><<<grid, blk, 0, stream>>>(Wb, A, nullptr, nullptr, C, M, N, K);
  } else {
    gemm_fb<2><<<grid, blk, 0, stream>>>(nullptr, A, Wq, S, C, M, N, K);
  }
}